// Round 1
// baseline (29294.153 us; speedup 1.0000x reference)
//
#include <hip/hip_runtime.h>
#include <math.h>

#define T_  128
#define B_  256
#define F_  128
#define H_  512
#define W_  16
#define NH_ 8
#define DK_ 64
#define H4_ 2048
#define EPS_ 1e-5f

__device__ __forceinline__ float eluf(float x){ return x > 0.f ? x : expf(x) - 1.f; }
__device__ __forceinline__ float sigf(float x){ return 1.f / (1.f + expf(-x)); }

// ---------------------------------------------------------------------------
// Generic multi-job tiled f32 GEMM:  out = act( A1@W1 + A2@W2 + bias1 + bias2 + addm )
// flags: 1 = elu epilogue, 2 = normalize A2 on load (BN with raw sums), 4 = emit BN partial sums
// Tiles: 32x32, 256 threads, KC=32.
// ---------------------------------------------------------------------------
struct GemmJob {
  const float* A1; const float* W1; int K1;
  const float* A2; const float* W2; int K2;
  const float* bias1; const float* bias2;
  const float* addm;
  const float* nsums;          // [2*H] raw sum / sumsq for NORM2 of A2 columns
  const float* ng; const float* nbe;
  float* out;
  float* statsOut;             // [2*N] atomic partial sums (flags&4)
  int N; int tiles; int nTilesN; int flags;
};
struct GemmArgs { GemmJob jobs[4]; int njobs; };

__global__ __launch_bounds__(256) void gemm_multi(GemmArgs ga) {
  int bid = blockIdx.x;
  int ji = 0;
  while (ji < ga.njobs - 1 && bid >= ga.jobs[ji].tiles) { bid -= ga.jobs[ji].tiles; ++ji; }
  GemmJob J = ga.jobs[ji];
  const int tmIdx = bid / J.nTilesN, tnIdx = bid % J.nTilesN;
  const int m0 = tmIdx * 32, n0 = tnIdx * 32;
  const int tid = threadIdx.x;
  const int tn2 = tid & 15, tm2 = tid >> 4;

  __shared__ float aT[32][33];
  __shared__ float wS[32][33];
  __shared__ float red[32][17];

  float acc00 = 0.f, acc01 = 0.f, acc10 = 0.f, acc11 = 0.f;

  for (int seg = 0; seg < 2; ++seg) {
    const float* A  = seg ? J.A2 : J.A1;
    const float* Wt = seg ? J.W2 : J.W1;
    const int    K  = seg ? J.K2 : J.K1;
    const bool  nrm = seg && (J.flags & 2);
    for (int kc = 0; kc < K; kc += 32) {
      __syncthreads();
      #pragma unroll
      for (int i = 0; i < 4; ++i) {
        int idx = tid + i * 256;          // 0..1023
        int mm = idx >> 5, kk = idx & 31;
        int gk = kc + kk;
        float v = A[(size_t)(m0 + mm) * K + gk];
        if (nrm) {
          float mu  = J.nsums[gk] * (1.f / B_);
          float var = J.nsums[H_ + gk] * (1.f / B_) - mu * mu;
          float rs  = rsqrtf(var + EPS_);
          v = (v - mu) * rs * J.ng[gk] + J.nbe[gk];
        }
        aT[kk][mm] = v;
        int kk2 = idx >> 5, nn = idx & 31;
        wS[kk2][nn] = Wt[(size_t)(kc + kk2) * J.N + n0 + nn];
      }
      __syncthreads();
      #pragma unroll
      for (int k = 0; k < 32; ++k) {
        float a0 = aT[k][tm2], a1 = aT[k][tm2 + 16];
        float w0 = wS[k][tn2], w1 = wS[k][tn2 + 16];
        acc00 += a0 * w0; acc01 += a0 * w1;
        acc10 += a1 * w0; acc11 += a1 * w1;
      }
    }
  }

  float b0 = 0.f, b1 = 0.f;
  if (J.bias1) { b0 += J.bias1[n0 + tn2]; b1 += J.bias1[n0 + tn2 + 16]; }
  if (J.bias2) { b0 += J.bias2[n0 + tn2]; b1 += J.bias2[n0 + tn2 + 16]; }
  const int mA = m0 + tm2, mB = m0 + tm2 + 16;
  const int nA = n0 + tn2, nB = n0 + tn2 + 16;
  float v00 = acc00 + b0, v01 = acc01 + b1;
  float v10 = acc10 + b0, v11 = acc11 + b1;
  if (J.addm) {
    v00 += J.addm[(size_t)mA * J.N + nA]; v01 += J.addm[(size_t)mA * J.N + nB];
    v10 += J.addm[(size_t)mB * J.N + nA]; v11 += J.addm[(size_t)mB * J.N + nB];
  }
  if (J.flags & 1) { v00 = eluf(v00); v01 = eluf(v01); v10 = eluf(v10); v11 = eluf(v11); }
  J.out[(size_t)mA * J.N + nA] = v00; J.out[(size_t)mA * J.N + nB] = v01;
  J.out[(size_t)mB * J.N + nA] = v10; J.out[(size_t)mB * J.N + nB] = v11;

  if (J.flags & 4) {
    __syncthreads();
    red[tn2][tm2]      = v00 + v10;
    red[tn2 + 16][tm2] = v01 + v11;
    __syncthreads();
    if (tid < 32) {
      float s = 0.f;
      for (int i = 0; i < 16; ++i) s += red[tid][i];
      atomicAdd(&J.statsOut[n0 + tid], s);
    }
    __syncthreads();
    red[tn2][tm2]      = v00 * v00 + v10 * v10;
    red[tn2 + 16][tm2] = v01 * v01 + v11 * v11;
    __syncthreads();
    if (tid < 32) {
      float s = 0.f;
      for (int i = 0; i < 16; ++i) s += red[tid][i];
      atomicAdd(&J.statsOut[H_ + n0 + tid], s);
    }
  }
}

// ---------------------------------------------------------------------------
// Attention: one block per batch row b. Reads Qh + cached K/V ring, writes ctx.
// Also zeroes statsAtt (block 0) for this step's BN-att accumulation.
// Ring slot for c_i is (i & 15); c_{-1} (initial zero row) lives in slot 15.
// Valid entries at step t: i = t-1 ... max(t-16, -1)  (nv = min(t+1,16)).
// ---------------------------------------------------------------------------
__global__ __launch_bounds__(256) void attn_kernel(const float* __restrict__ Qh,
                                                   const float* __restrict__ Kbuf,
                                                   const float* __restrict__ Vbuf,
                                                   float* __restrict__ ctx,
                                                   float* __restrict__ statsAtt, int t) {
  const int b = blockIdx.x, tid = threadIdx.x;
  if (b == 0) {
    for (int i = tid; i < 2 * H_; i += 256) statsAtt[i] = 0.f;
  }
  __shared__ float Qs[H_];
  __shared__ float Ks[W_][H_];
  __shared__ float Vs[W_][H_];
  __shared__ float sc[NH_][W_];
  __shared__ float aw[NH_][W_];
  const int nv = min(t + 1, W_);
  for (int i = tid; i < H_; i += 256) Qs[i] = Qh[(size_t)b * H_ + i];
  for (int idx = tid; idx < nv * H_; idx += 256) {
    int jj = idx >> 9;            // 0..nv-1, jj=0 is newest (i = t-1)
    int d  = idx & (H_ - 1);
    int slot = (t - 1 - jj) & (W_ - 1);
    Ks[jj][d] = Kbuf[(size_t)slot * B_ * H_ + (size_t)b * H_ + d];
    Vs[jj][d] = Vbuf[(size_t)slot * B_ * H_ + (size_t)b * H_ + d];
  }
  __syncthreads();
  if (tid < NH_ * W_) {
    int hh = tid >> 4, jj = tid & 15;
    if (jj < nv) {
      float s = 0.f;
      const float* qp = &Qs[hh * DK_];
      const float* kp = &Ks[jj][hh * DK_];
      #pragma unroll
      for (int d = 0; d < DK_; ++d) s += qp[d] * kp[d];
      sc[hh][jj] = s * 0.125f;    // 1/sqrt(DK)
    }
  }
  __syncthreads();
  if (tid < NH_) {
    int hh = tid;
    float mx = -1e30f;
    for (int jj = 0; jj < nv; ++jj) mx = fmaxf(mx, sc[hh][jj]);
    float ssum = 0.f;
    for (int jj = 0; jj < nv; ++jj) { float e = expf(sc[hh][jj] - mx); aw[hh][jj] = e; ssum += e; }
    float inv = 1.f / ssum;
    for (int jj = 0; jj < nv; ++jj) aw[hh][jj] *= inv;
  }
  __syncthreads();
  for (int idx = tid; idx < H_; idx += 256) {
    int hh = idx >> 6;
    float s = 0.f;
    for (int jj = 0; jj < nv; ++jj) s += aw[hh][jj] * Vs[jj][idx];
    ctx[(size_t)b * H_ + idx] = s;
  }
}

// ---------------------------------------------------------------------------
// Gates: pre (B x 4H) + c -> c_new, hp = o_g * elu(c_new); direct (non-atomic)
// BN-post column sums (each block owns 64 columns, all 256 rows).
// ---------------------------------------------------------------------------
__global__ __launch_bounds__(256) void gates_kernel(const float* __restrict__ pre,
                                                    float* __restrict__ c,
                                                    float* __restrict__ hp,
                                                    float* __restrict__ statsPost) {
  const int blk = blockIdx.x;          // 8 blocks
  const int tid = threadIdx.x;
  const int col = blk * 64 + (tid & 63);
  const int rg  = tid >> 6;            // 0..3
  float s = 0.f, s2 = 0.f;
  for (int r = rg * 64; r < rg * 64 + 64; ++r) {
    float p0 = pre[(size_t)r * H4_ + col];
    float pf = pre[(size_t)r * H4_ + col + H_];
    float pi = pre[(size_t)r * H4_ + col + 2 * H_];
    float po = pre[(size_t)r * H4_ + col + 3 * H_];
    float iv = tanhf(p0);
    float fg = sigf(pf), ig = sigf(pi), og = sigf(po);
    float cold = c[(size_t)r * H_ + col];
    float cn = iv * ig + cold * fg;
    c[(size_t)r * H_ + col] = cn;
    float hv = og * eluf(cn);
    hp[(size_t)r * H_ + col] = hv;
    s += hv; s2 += hv * hv;
  }
  __shared__ float redS[64][5];
  __shared__ float redQ[64][5];
  redS[tid & 63][rg] = s;
  redQ[tid & 63][rg] = s2;
  __syncthreads();
  if (tid < 64) {
    float a = 0.f, b2 = 0.f;
    for (int i = 0; i < 4; ++i) { a += redS[tid][i]; b2 += redQ[tid][i]; }
    statsPost[col - (tid & 63) + tid] = a;                  // = statsPost[blk*64+tid]
    statsPost[H_ + blk * 64 + tid] = b2;
  }
}

// h_new = BN(hp) -> h buffer + d_out[t]
__global__ __launch_bounds__(256) void hout_kernel(const float* __restrict__ hp,
                                                   const float* __restrict__ statsPost,
                                                   const float* __restrict__ g,
                                                   const float* __restrict__ be,
                                                   float* __restrict__ h,
                                                   float* __restrict__ outT) {
  const int idx = blockIdx.x * 256 + threadIdx.x;    // < B*H
  const int col = idx & (H_ - 1);
  float mu  = statsPost[col] * (1.f / B_);
  float var = statsPost[H_ + col] * (1.f / B_) - mu * mu;
  float rs  = rsqrtf(var + EPS_);
  float v = (hp[idx] - mu) * rs * g[col] + be[col];
  h[idx] = v;
  outT[idx] = v;
}

__global__ __launch_bounds__(256) void init_kernel(float* h, float* c, float* Kbuf, float* Vbuf,
                                                   const float* bk, const float* bv) {
  const int idx = blockIdx.x * 256 + threadIdx.x;
  if (idx < B_ * H_) {
    h[idx] = 0.f; c[idx] = 0.f;
    int col = idx & (H_ - 1);
    Kbuf[(size_t)15 * B_ * H_ + idx] = eluf(bk[col]);
    Vbuf[(size_t)15 * B_ * H_ + idx] = eluf(bv[col]);
  }
}

static inline GemmJob mkjob(const float* A1, const float* W1, int K1,
                            const float* A2, const float* W2, int K2,
                            const float* b1, const float* b2,
                            const float* addm, float* outp, int N, int flags,
                            const float* nsums, const float* ng, const float* nbe,
                            float* statsOut) {
  GemmJob j;
  j.A1 = A1; j.W1 = W1; j.K1 = K1;
  j.A2 = A2; j.W2 = W2; j.K2 = K2;
  j.bias1 = b1; j.bias2 = b2; j.addm = addm;
  j.nsums = nsums; j.ng = ng; j.nbe = nbe;
  j.out = outp; j.statsOut = statsOut;
  j.N = N; j.nTilesN = N / 32; j.tiles = (B_ / 32) * (N / 32); j.flags = flags;
  return j;
}

extern "C" void kernel_launch(void* const* d_in, const int* in_sizes, int n_in,
                              void* d_out, int out_size, void* d_ws, size_t ws_size,
                              hipStream_t stream) {
  const float* x      = (const float*)d_in[0];
  const float* W_ih   = (const float*)d_in[1];
  const float* b_ih   = (const float*)d_in[2];
  const float* W_hh   = (const float*)d_in[3];
  const float* Wq_in  = (const float*)d_in[4];
  const float* bq_in  = (const float*)d_in[5];
  const float* Wq     = (const float*)d_in[6];
  const float* bq     = (const float*)d_in[7];
  const float* Wk     = (const float*)d_in[8];
  const float* bk     = (const float*)d_in[9];
  const float* Wv     = (const float*)d_in[10];
  const float* bv     = (const float*)d_in[11];
  const float* Wo     = (const float*)d_in[12];
  const float* bo     = (const float*)d_in[13];
  const float* W_ac   = (const float*)d_in[14];
  const float* b_ac   = (const float*)d_in[15];
  const float* g_att  = (const float*)d_in[16];
  const float* be_att = (const float*)d_in[17];
  const float* g_post = (const float*)d_in[18];
  const float* be_post= (const float*)d_in[19];
  float* out = (float*)d_out;
  float* ws  = (float*)d_ws;

  // ws layout (floats)
  float* h    = ws;                         // B*H
  float* c    = h    + (size_t)B_ * H_;
  float* q    = c    + (size_t)B_ * H_;
  float* Qh   = q    + (size_t)B_ * H_;
  float* ctx  = Qh   + (size_t)B_ * H_;
  float* attp = ctx  + (size_t)B_ * H_;
  float* hp   = attp + (size_t)B_ * H_;
  float* hWhh = hp   + (size_t)B_ * H_;     // B*4H
  float* pre  = hWhh + (size_t)B_ * H4_;    // B*4H
  float* Kbuf = pre  + (size_t)B_ * H4_;    // W*B*H
  float* Vbuf = Kbuf + (size_t)W_ * B_ * H_;
  float* stA  = Vbuf + (size_t)W_ * B_ * H_; // 2*H
  float* stP  = stA  + 2 * H_;               // 2*H

  init_kernel<<<(B_ * H_ + 255) / 256, 256, 0, stream>>>(h, c, Kbuf, Vbuf, bk, bv);

  for (int t = 0; t < T_; ++t) {
    const float* xt = x + (size_t)t * B_ * F_;

    // ---- G1: q = elu(x_t@Wqx + h@Wqh + bq_in); hWhh = h@W_hh; K/V ring update
    GemmArgs ga; ga.njobs = 0;
    ga.jobs[ga.njobs++] = mkjob(xt, Wq_in, F_, h, Wq_in + (size_t)F_ * H_, H_,
                                bq_in, nullptr, nullptr, q, H_, 1,
                                nullptr, nullptr, nullptr, nullptr);
    ga.jobs[ga.njobs++] = mkjob(h, W_hh, H_, nullptr, nullptr, 0,
                                nullptr, nullptr, nullptr, hWhh, H4_, 0,
                                nullptr, nullptr, nullptr, nullptr);
    if (t >= 1) {
      int slot = (t - 1) & (W_ - 1);
      ga.jobs[ga.njobs++] = mkjob(c, Wk, H_, nullptr, nullptr, 0,
                                  bk, nullptr, nullptr, Kbuf + (size_t)slot * B_ * H_, H_, 1,
                                  nullptr, nullptr, nullptr, nullptr);
      ga.jobs[ga.njobs++] = mkjob(c, Wv, H_, nullptr, nullptr, 0,
                                  bv, nullptr, nullptr, Vbuf + (size_t)slot * B_ * H_, H_, 1,
                                  nullptr, nullptr, nullptr, nullptr);
    }
    int tiles1 = 0;
    for (int i = 0; i < ga.njobs; ++i) tiles1 += ga.jobs[i].tiles;
    gemm_multi<<<tiles1, 256, 0, stream>>>(ga);

    // ---- G2: Qh = q@Wq + bq
    GemmArgs g2; g2.njobs = 1;
    g2.jobs[0] = mkjob(q, Wq, H_, nullptr, nullptr, 0, bq, nullptr, nullptr,
                       Qh, H_, 0, nullptr, nullptr, nullptr, nullptr);
    gemm_multi<<<g2.jobs[0].tiles, 256, 0, stream>>>(g2);

    // ---- B2: attention -> ctx (also zeroes stA)
    attn_kernel<<<B_, 256, 0, stream>>>(Qh, Kbuf, Vbuf, ctx, stA, t);

    // ---- B3: att_pre = elu(ctx@Wo + bo) with BN partial sums -> stA
    GemmArgs g3; g3.njobs = 1;
    g3.jobs[0] = mkjob(ctx, Wo, H_, nullptr, nullptr, 0, bo, nullptr, nullptr,
                       attp, H_, 1 | 4, nullptr, nullptr, nullptr, stA);
    gemm_multi<<<g3.jobs[0].tiles, 256, 0, stream>>>(g3);

    // ---- G4: pre = x_t@W_ih + BN(att_pre)@W_ac + hWhh + b_ih + b_ac
    GemmArgs g4; g4.njobs = 1;
    g4.jobs[0] = mkjob(xt, W_ih, F_, attp, W_ac, H_, b_ih, b_ac, hWhh,
                       pre, H4_, 2, stA, g_att, be_att, nullptr);
    gemm_multi<<<g4.jobs[0].tiles, 256, 0, stream>>>(g4);

    // ---- D: gates -> c_new, hp, statsPost
    gates_kernel<<<8, 256, 0, stream>>>(pre, c, hp, stP);

    // ---- E: h = BN(hp), write output row t
    hout_kernel<<<(B_ * H_) / 256, 256, 0, stream>>>(hp, stP, g_post, be_post,
                                                     h, out + (size_t)t * B_ * H_);
  }
}

// Round 3
// 27597.763 us; speedup vs baseline: 1.0615x; 1.0615x over previous
//
#include <hip/hip_runtime.h>
#include <math.h>

// ============================================================================
// LARNN forward, MI355X. ALL-F32 BY NECESSITY:
// The recurrence is chaotic (near-degenerate BatchNorm columns: ref absmax
// 15.6 ~ sqrt(B-1) one-outlier z-score bound; 128 recurrent steps). Full-f32
// round-1 kernel already showed absmax err 0.0625 (~1e5x the f32 noise floor).
// bf16 anywhere (round 2) gave err 17.6 ~ decorrelated saturation. Therefore:
// no bf16, no MFMA (CDNA4 has no fp32 MFMA); f32 vector ALU only.
// Also: deterministic BN stats (per-m-tile partials, no float atomics) since
// atomic-order noise would be amplified by the same ~1e4-1e5 factor.
// ============================================================================

#define T_  128
#define B_  256
#define F_  128
#define H_  512
#define W_  16
#define H4_ 2048
#define EPS_ 1e-5f
#define BH_ (B_*H_)

typedef __attribute__((ext_vector_type(4))) float f4;

__device__ __forceinline__ float eluf(float x){ return x > 0.f ? x : expf(x) - 1.f; }
__device__ __forceinline__ float sigf(float x){ return 1.f / (1.f + expf(-x)); }

// ---------------------------------------------------------------------------
// Multi-job, multi-K-segment f32 GEMM.  out = act( sum_s A_s@W_s + b1 + b2 )
// Tile 64x64, 256 threads, 4x4 microtile, KC=32.
// Job flags: 1 = elu epilogue, 2 = this job has a normalized segment,
//            4 = emit per-m-tile BN partial sums (deterministic, no atomics).
// Seg.norm: apply BN (from ga.nsums partials, ga.ng/nbe) to A on load.
// W layout: original row-major [K][N], stride = J.N.
// ---------------------------------------------------------------------------
struct Seg3 { const float* A; int lda; const float* W; int K; int norm; };
struct Job3 {
  Seg3 seg[3]; int nseg;
  const float* bias1; const float* bias2;
  float* out; float* statsOut;       // statsOut: [4 m-tiles][2][512]
  int N; int tilesN; int tiles; int flags;
};
struct GA3 {
  Job3 jobs[3]; int njobs;
  const float* nsums;                // [4][2][512] partials (sum, sumsq)
  const float* ng; const float* nbe;
};

__global__ __launch_bounds__(256) void gemm3(GA3 ga) {
  int bid = blockIdx.x, ji = 0;
  while (ji < ga.njobs - 1 && bid >= ga.jobs[ji].tiles) { bid -= ga.jobs[ji].tiles; ++ji; }
  const Job3& J = ga.jobs[ji];
  const int tm = bid / J.tilesN, tn = bid % J.tilesN;
  const int m0 = tm * 64, n0 = tn * 64;
  const int tid = threadIdx.x;
  const int ty = tid >> 4, tx = tid & 15;

  __shared__ float As[32][68];
  __shared__ float Bs[32][68];
  __shared__ float nscl[H_], nshf[H_];

  // Precompute BN scale/shift for the normalized segment (deterministic sums).
  if (J.flags & 2) {
    for (int i = tid; i < H_; i += 256) {
      float S = 0.f, S2 = 0.f;
      #pragma unroll
      for (int m = 0; m < 4; ++m) { S += ga.nsums[m * 1024 + i]; S2 += ga.nsums[m * 1024 + 512 + i]; }
      float mu  = S * (1.f / B_);
      float var = S2 * (1.f / B_) - mu * mu;
      float rs  = rsqrtf(var + EPS_);
      float sc  = rs * ga.ng[i];
      nscl[i] = sc; nshf[i] = ga.nbe[i] - mu * sc;
    }
  }

  float acc[4][4] = {};

  for (int s = 0; s < J.nseg; ++s) {
    const Seg3 S = J.seg[s];
    for (int kc = 0; kc < S.K; kc += 32) {
      __syncthreads();
      // A: 64 rows x 32 k, stored transposed As[k][m]
      {
        const int row = tid >> 3, kq = (tid & 7) * 4;
        #pragma unroll
        for (int half = 0; half < 2; ++half) {
          int rr = row + half * 32;
          f4 v = *(const f4*)(S.A + (size_t)(m0 + rr) * S.lda + kc + kq);
          if (S.norm) {
            #pragma unroll
            for (int i = 0; i < 4; ++i) {
              int gk = kc + kq + i;
              v[i] = v[i] * nscl[gk] + nshf[gk];
            }
          }
          #pragma unroll
          for (int i = 0; i < 4; ++i) As[kq + i][rr] = v[i];
        }
      }
      // B: 32 k x 64 n
      {
        const int kk = tid >> 4, nn = (tid & 15) * 4;
        #pragma unroll
        for (int half = 0; half < 2; ++half) {
          f4 w = *(const f4*)(S.W + (size_t)(kc + kk + half * 16) * J.N + n0 + nn);
          *(f4*)&Bs[kk + half * 16][nn] = w;
        }
      }
      __syncthreads();
      #pragma unroll
      for (int k = 0; k < 32; ++k) {
        f4 a = *(const f4*)&As[k][ty * 4];
        f4 b = *(const f4*)&Bs[k][tx * 4];
        #pragma unroll
        for (int i = 0; i < 4; ++i)
          #pragma unroll
          for (int j = 0; j < 4; ++j)
            acc[i][j] = fmaf(a[i], b[j], acc[i][j]);
      }
    }
  }

  const int rbase = m0 + ty * 4, cbase = n0 + tx * 4;
  float bias[4];
  #pragma unroll
  for (int j = 0; j < 4; ++j) {
    float bb = 0.f;
    if (J.bias1) bb += J.bias1[cbase + j];
    if (J.bias2) bb += J.bias2[cbase + j];
    bias[j] = bb;
  }
  #pragma unroll
  for (int i = 0; i < 4; ++i)
    #pragma unroll
    for (int j = 0; j < 4; ++j) {
      float v = acc[i][j] + bias[j];
      if (J.flags & 1) v = eluf(v);
      acc[i][j] = v;
      J.out[(size_t)(rbase + i) * J.N + cbase + j] = v;
    }

  if (J.flags & 4) {
    __syncthreads();
    #pragma unroll
    for (int j = 0; j < 4; ++j) {
      float s = 0.f, q2 = 0.f;
      #pragma unroll
      for (int i = 0; i < 4; ++i) { s += acc[i][j]; q2 += acc[i][j] * acc[i][j]; }
      As[ty][tx * 4 + j] = s;
      Bs[ty][tx * 4 + j] = q2;
    }
    __syncthreads();
    if (tid < 64) {
      float S = 0.f, S2 = 0.f;
      #pragma unroll
      for (int yy = 0; yy < 16; ++yy) { S += As[yy][tid]; S2 += Bs[yy][tid]; }
      J.statsOut[tm * 1024 + n0 + tid] = S;
      J.statsOut[tm * 1024 + 512 + n0 + tid] = S2;
    }
  }
}

// ---------------------------------------------------------------------------
// Attention, one block per batch row, 128 threads. No LDS K/V staging (each
// element read exactly once -> staging is pure overhead; ring is L2-hot).
// Ring slot of c_i = i & 15; c_{-1} (zero state, K/V = elu(bias)) in slot 15.
// Valid at step t: nv = min(t+1,16) entries, slots (t-1-w)&15, w=0..nv-1.
// ---------------------------------------------------------------------------
__global__ __launch_bounds__(128) void attn3(const float* __restrict__ Qh,
                                             const float* __restrict__ Kbuf,
                                             const float* __restrict__ Vbuf,
                                             float* __restrict__ ctx, int t) {
  const int b = blockIdx.x, tid = threadIdx.x;
  __shared__ float Qs[H_];
  __shared__ float aw[8][16];
  const int nv = min(t + 1, W_);

  *(f4*)&Qs[tid * 4] = *(const f4*)(Qh + (size_t)b * H_ + tid * 4);
  __syncthreads();

  {
    int hh = tid >> 4, jj = tid & 15;
    if (jj < nv) {
      int slot = (t - 1 - jj) & 15;
      const float* kp = Kbuf + ((size_t)slot * B_ + b) * H_ + hh * 64;
      const float* qp = &Qs[hh * 64];
      float s = 0.f;
      #pragma unroll
      for (int d = 0; d < 64; d += 4) {
        f4 kv = *(const f4*)(kp + d);
        f4 qv = *(const f4*)(qp + d);
        s = fmaf(kv[0], qv[0], fmaf(kv[1], qv[1], fmaf(kv[2], qv[2], fmaf(kv[3], qv[3], s))));
      }
      aw[hh][jj] = s * 0.125f;   // raw scaled score
    }
  }
  __syncthreads();
  if (tid < 8) {
    float mx = -1e30f;
    for (int j = 0; j < nv; ++j) mx = fmaxf(mx, aw[tid][j]);
    float ss = 0.f;
    for (int j = 0; j < nv; ++j) { float e = expf(aw[tid][j] - mx); aw[tid][j] = e; ss += e; }
    float inv = 1.f / ss;
    for (int j = 0; j < nv; ++j) aw[tid][j] *= inv;
  }
  __syncthreads();
  {
    int hh = tid >> 4;
    f4 o = {0.f, 0.f, 0.f, 0.f};
    for (int w = 0; w < nv; ++w) {
      int slot = (t - 1 - w) & 15;
      float a_ = aw[hh][w];
      f4 v = *(const f4*)(Vbuf + ((size_t)slot * B_ + b) * H_ + tid * 4);
      o[0] = fmaf(a_, v[0], o[0]); o[1] = fmaf(a_, v[1], o[1]);
      o[2] = fmaf(a_, v[2], o[2]); o[3] = fmaf(a_, v[3], o[3]);
    }
    *(f4*)(ctx + (size_t)b * H_ + tid * 4) = o;
  }
}

// ---------------------------------------------------------------------------
// Gates + BatchNorm(post) + output. 8 blocks, block owns 64 cols x all 256
// rows; in-block deterministic stats. Stashes hv into pre[:, col] (iv slot,
// dead after read).
// ---------------------------------------------------------------------------
__global__ __launch_bounds__(256) void gates3(float* __restrict__ pre, float* __restrict__ c,
                                              float* __restrict__ h,
                                              const float* __restrict__ g_post,
                                              const float* __restrict__ be_post,
                                              float* __restrict__ outT) {
  const int blk = blockIdx.x, tid = threadIdx.x;
  const int cl = tid & 63, q = tid >> 6;
  const int gcol = blk * 64 + cl;
  float s = 0.f, s2 = 0.f;
  for (int r = q * 64; r < q * 64 + 64; ++r) {
    size_t rb = (size_t)r * H4_;
    float p0 = pre[rb + gcol];
    float pf = pre[rb + gcol + H_];
    float pi = pre[rb + gcol + 2 * H_];
    float po = pre[rb + gcol + 3 * H_];
    float iv = tanhf(p0);
    float fg = sigf(pf), ig = sigf(pi), og = sigf(po);
    size_t ci = (size_t)r * H_ + gcol;
    float cn = iv * ig + c[ci] * fg;
    c[ci] = cn;
    float hv = og * eluf(cn);
    pre[rb + gcol] = hv;                 // stash
    s += hv; s2 += hv * hv;
  }
  __shared__ float ps[4][64], ps2[4][64], scl[64], shf[64];
  ps[q][cl] = s; ps2[q][cl] = s2;
  __syncthreads();
  if (tid < 64) {
    float S = 0.f, S2 = 0.f;
    #pragma unroll
    for (int i = 0; i < 4; ++i) { S += ps[i][tid]; S2 += ps2[i][tid]; }
    float mu = S * (1.f / B_), var = S2 * (1.f / B_) - mu * mu;
    float rs = rsqrtf(var + EPS_);
    float sc = rs * g_post[blk * 64 + tid];
    scl[tid] = sc; shf[tid] = be_post[blk * 64 + tid] - mu * sc;
  }
  __syncthreads();
  for (int r = q * 64; r < q * 64 + 64; ++r) {
    float v = pre[(size_t)r * H4_ + gcol] * scl[cl] + shf[cl];
    size_t ci = (size_t)r * H_ + gcol;
    h[ci] = v;
    outT[ci] = v;
  }
}

__global__ __launch_bounds__(256) void init3(float* h, float* c, float* Kbuf, float* Vbuf,
                                             const float* bk, const float* bv) {
  const int idx = blockIdx.x * 256 + threadIdx.x;   // < B*H
  const int col = idx & (H_ - 1);
  h[idx] = 0.f; c[idx] = 0.f;
  Kbuf[(size_t)15 * BH_ + idx] = eluf(bk[col]);
  Vbuf[(size_t)15 * BH_ + idx] = eluf(bv[col]);
}

extern "C" void kernel_launch(void* const* d_in, const int* in_sizes, int n_in,
                              void* d_out, int out_size, void* d_ws, size_t ws_size,
                              hipStream_t stream) {
  const float* x      = (const float*)d_in[0];
  const float* W_ih   = (const float*)d_in[1];
  const float* b_ih   = (const float*)d_in[2];
  const float* W_hh   = (const float*)d_in[3];
  const float* Wq_in  = (const float*)d_in[4];
  const float* bq_in  = (const float*)d_in[5];
  const float* Wq     = (const float*)d_in[6];
  const float* bq     = (const float*)d_in[7];
  const float* Wk     = (const float*)d_in[8];
  const float* bk     = (const float*)d_in[9];
  const float* Wv     = (const float*)d_in[10];
  const float* bv     = (const float*)d_in[11];
  const float* Wo     = (const float*)d_in[12];
  const float* bo     = (const float*)d_in[13];
  const float* W_ac   = (const float*)d_in[14];
  const float* b_ac   = (const float*)d_in[15];
  const float* g_att  = (const float*)d_in[16];
  const float* be_att = (const float*)d_in[17];
  const float* g_post = (const float*)d_in[18];
  const float* be_post= (const float*)d_in[19];
  float* out = (float*)d_out;
  float* ws  = (float*)d_ws;

  // ws layout (floats): ~22.0 MB total (round-1 proved >= 23.7 MB available)
  float* h    = ws;                          // B*H
  float* c    = h    + BH_;
  float* q    = c    + BH_;
  float* Qh   = q    + BH_;
  float* ctx  = Qh   + BH_;
  float* attp = ctx  + BH_;
  float* pre  = attp + BH_;                  // B*4H
  float* Kbuf = pre  + (size_t)B_ * H4_;     // W*B*H
  float* Vbuf = Kbuf + (size_t)W_ * BH_;
  float* stA4 = Vbuf + (size_t)W_ * BH_;     // 4*2*512 partials

  init3<<<BH_ / 256, 256, 0, stream>>>(h, c, Kbuf, Vbuf, bk, bv);

  for (int t = 0; t < T_; ++t) {
    const float* xt = x + (size_t)t * B_ * F_;

    // ---- S1: q = elu([x_t,h]@Wq_in + bq_in); K/V ring update from c ----
    GA3 ga = {}; int nj = 0;
    {
      Job3 j = {}; j.nseg = 2;
      j.seg[0] = { xt, F_, Wq_in,             F_, 0 };
      j.seg[1] = { h,  H_, Wq_in + 128 * H_,  H_, 0 };
      j.bias1 = bq_in; j.out = q;
      j.N = H_; j.tilesN = 8; j.tiles = 32; j.flags = 1;
      ga.jobs[nj++] = j;
    }
    if (t >= 1) {
      int slot = (t - 1) & 15;
      Job3 jk = {}; jk.nseg = 1;
      jk.seg[0] = { c, H_, Wk, H_, 0 };
      jk.bias1 = bk; jk.out = Kbuf + (size_t)slot * BH_;
      jk.N = H_; jk.tilesN = 8; jk.tiles = 32; jk.flags = 1;
      ga.jobs[nj++] = jk;
      Job3 jv = jk;
      jv.seg[0].W = Wv; jv.bias1 = bv; jv.out = Vbuf + (size_t)slot * BH_;
      ga.jobs[nj++] = jv;
    }
    ga.njobs = nj;
    gemm3<<<32 * nj, 256, 0, stream>>>(ga);

    // ---- S2: Qh = q@Wq + bq ----
    GA3 g2 = {}; g2.njobs = 1;
    {
      Job3 j = {}; j.nseg = 1;
      j.seg[0] = { q, H_, Wq, H_, 0 };
      j.bias1 = bq; j.out = Qh;
      j.N = H_; j.tilesN = 8; j.tiles = 32; j.flags = 0;
      g2.jobs[0] = j;
    }
    gemm3<<<32, 256, 0, stream>>>(g2);

    // ---- S3: attention -> ctx ----
    attn3<<<B_, 128, 0, stream>>>(Qh, Kbuf, Vbuf, ctx, t);

    // ---- S4: attp = elu(ctx@Wo + bo), deterministic BN partials -> stA4 ----
    GA3 g4 = {}; g4.njobs = 1;
    {
      Job3 j = {}; j.nseg = 1;
      j.seg[0] = { ctx, H_, Wo, H_, 0 };
      j.bias1 = bo; j.out = attp; j.statsOut = stA4;
      j.N = H_; j.tilesN = 8; j.tiles = 32; j.flags = 1 | 4;
      g4.jobs[0] = j;
    }
    gemm3<<<32, 256, 0, stream>>>(g4);

    // ---- S5: pre = x_t@W_ih + BN(attp)@W_ac + h@W_hh + b_ih + b_ac ----
    GA3 g5 = {}; g5.njobs = 1;
    g5.nsums = stA4; g5.ng = g_att; g5.nbe = be_att;
    {
      Job3 j = {}; j.nseg = 3;
      j.seg[0] = { xt,   F_, W_ih, F_, 0 };
      j.seg[1] = { attp, H_, W_ac, H_, 1 };
      j.seg[2] = { h,    H_, W_hh, H_, 0 };
      j.bias1 = b_ih; j.bias2 = b_ac; j.out = pre;
      j.N = H4_; j.tilesN = 32; j.tiles = 128; j.flags = 2;
      g5.jobs[0] = j;
    }
    gemm3<<<128, 256, 0, stream>>>(g5);

    // ---- S6: gates + BN(post) -> c, h, out[t] ----
    gates3<<<H_ / 64, 256, 0, stream>>>(pre, c, h, g_post, be_post,
                                        out + (size_t)t * BH_);
  }
}